// Round 1
// baseline (1167.164 us; speedup 1.0000x reference)
//
#include <hip/hip_runtime.h>
#include <math.h>

// Problem constants: B=1, CIN=COUT=32, KS=3 (K=27), D=32, H=W=64, stride=1, pad=1, dil=1
#define DD 32
#define HH 64
#define WW 64
#define CSTRIDE (DD * HH * WW)   // 131072: channel stride for x and out

// ---------------------------------------------------------------------------
// Weight transpose: wt2[tap][ci][co108] (co 0..80 = w_off, 81..107 = w_mask),
//                   wt3[tap][ci][co32]  (einsum weights)
// Contiguous-in-co layout lets the main kernel fetch weights with uniform
// scalar loads (s_load_dwordx8) — zero VMEM/VALU cost per FMA.
// ---------------------------------------------------------------------------
__global__ __launch_bounds__(256) void transpose_w_kernel(
    const float* __restrict__ w_off, const float* __restrict__ w_mask,
    const float* __restrict__ w, float* __restrict__ wt2, float* __restrict__ wt3)
{
    int i = blockIdx.x * 256 + threadIdx.x;
    if (i < 93312) {                       // 27*32*108
        int co  = i % 108;
        int ci  = (i / 108) % 32;
        int tap = i / (108 * 32);
        float v = (co < 81) ? w_off[(co * 32 + ci) * 27 + tap]
                            : w_mask[((co - 81) * 32 + ci) * 27 + tap];
        wt2[i] = v;
    } else if (i < 120960) {               // + 27*32*32
        int j   = i - 93312;
        int co  = j % 32;
        int ci  = (j / 32) % 32;
        int tap = j / 1024;
        wt3[j] = w[(co * 32 + ci) * 27 + tap];
    }
}

// ---------------------------------------------------------------------------
// Fused kernel: one block per (d,h) row of 64 output positions.
// Phase 1: 3x3x3 conv -> 81 offset + 27 mask channels, kept in LDS.
// Phase 2: per k-tap: trilinear sample (masked) into LDS, then einsum FMA.
// Thread map: t = w + 64*g;  g = co-group (27 conv channels / 8 einsum couts).
// ---------------------------------------------------------------------------
__global__ __launch_bounds__(256) void deform_fused_kernel(
    const float* __restrict__ x,
    const float* __restrict__ b_off, const float* __restrict__ b_mask,
    const float* __restrict__ bias,
    const float* __restrict__ wt2, const float* __restrict__ wt3,
    float* __restrict__ out)
{
    __shared__ float offm[108 * 64];   // [ch][w]   27.6 KB
    __shared__ float sbuf[32 * 65];    // [c][w] pitch 65 (conflict-free)  8.3 KB

    const int t  = threadIdx.x;
    const int lw = t & 63;                       // w coordinate (lane)
    const int g  = t >> 6;                       // 0..3 co-group
    const int gu = __builtin_amdgcn_readfirstlane(g);  // force wave-uniform
    const int d  = blockIdx.x >> 6;
    const int h  = blockIdx.x & 63;

    // ---------------- Phase 1: offset/mask conv ----------------
    float acc[27];
#pragma unroll
    for (int j = 0; j < 27; j++) acc[j] = 0.f;

    for (int kz = 0; kz < 3; kz++) {
        int z = d + kz - 1;
        if ((unsigned)z >= (unsigned)DD) continue;       // uniform branch
        for (int ky = 0; ky < 3; ky++) {
            int y = h + ky - 1;
            if ((unsigned)y >= (unsigned)HH) continue;   // uniform branch
            for (int kx = 0; kx < 3; kx++) {
                int xx = lw + kx - 1;
                bool ok = (unsigned)xx < (unsigned)WW;   // per-lane only at w edges
                int sidx = (z * HH + y) * WW + (ok ? xx : 0);
                const float* __restrict__ wrow =
                    wt2 + ((kz * 3 + ky) * 3 + kx) * (32 * 108) + gu * 27;
#pragma unroll 2
                for (int ci = 0; ci < 32; ci++) {
                    float xv = ok ? x[ci * CSTRIDE + sidx] : 0.f;
#pragma unroll
                    for (int j = 0; j < 27; j++)
                        acc[j] = fmaf(xv, wrow[ci * 108 + j], acc[j]);
                }
            }
        }
    }

#pragma unroll
    for (int j = 0; j < 27; j++) {
        int ch = gu * 27 + j;
        float v = acc[j] + (ch < 81 ? b_off[ch] : b_mask[ch - 81]);
        if (ch >= 81) v = 1.f / (1.f + __expf(-v));      // sigmoid for mask channels
        offm[ch * 64 + lw] = v;
    }
    __syncthreads();

    // ---------------- Phase 2: deformable sampling + einsum ----------------
    float acc2[8];
#pragma unroll
    for (int j = 0; j < 8; j++) acc2[j] = 0.f;
    const int c0 = g * 8;

    for (int k = 0; k < 27; k++) {
        float oz = offm[(k)      * 64 + lw];
        float oy = offm[(27 + k) * 64 + lw];
        float ox = offm[(54 + k) * 64 + lw];
        float m  = offm[(81 + k) * 64 + lw];
        int kz = k / 9, ky = (k / 3) % 3, kx = k % 3;

        float zc = (float)(d + kz - 1) + oz;
        float yc = (float)(h + ky - 1) + oy;
        float xc = (float)(lw + kx - 1) + ox;
        float zf = floorf(zc), yf = floorf(yc), xf = floorf(xc);
        int z0 = (int)zf, y0 = (int)yf, x0 = (int)xf;
        float fz = zc - zf, fy = yc - yf, fx = xc - xf;

        // fold per-axis validity (zero padding) into the lerp weights
        float wz0 = (z0 >= 0 && z0 < DD)         ? (1.f - fz) : 0.f;
        float wz1 = (z0 + 1 >= 0 && z0 + 1 < DD) ? fz         : 0.f;
        float wy0 = (y0 >= 0 && y0 < HH)         ? (1.f - fy) : 0.f;
        float wy1 = (y0 + 1 >= 0 && y0 + 1 < HH) ? fy         : 0.f;
        float wx0 = (x0 >= 0 && x0 < WW)         ? (1.f - fx) : 0.f;
        float wx1 = (x0 + 1 >= 0 && x0 + 1 < WW) ? fx         : 0.f;

        int iz0 = min(max(z0, 0), DD - 1),     iz1 = min(max(z0 + 1, 0), DD - 1);
        int iy0 = min(max(y0, 0), HH - 1),     iy1 = min(max(y0 + 1, 0), HH - 1);
        int ix0 = min(max(x0, 0), WW - 1),     ix1 = min(max(x0 + 1, 0), WW - 1);

        int o00 = (iz0 * HH + iy0) * WW, o01 = (iz0 * HH + iy1) * WW;
        int o10 = (iz1 * HH + iy0) * WW, o11 = (iz1 * HH + iy1) * WW;

        float cw0 = wz0 * wy0 * wx0, cw1 = wz0 * wy0 * wx1;
        float cw2 = wz0 * wy1 * wx0, cw3 = wz0 * wy1 * wx1;
        float cw4 = wz1 * wy0 * wx0, cw5 = wz1 * wy0 * wx1;
        float cw6 = wz1 * wy1 * wx0, cw7 = wz1 * wy1 * wx1;
        int of0 = o00 + ix0, of1 = o00 + ix1, of2 = o01 + ix0, of3 = o01 + ix1;
        int of4 = o10 + ix0, of5 = o10 + ix1, of6 = o11 + ix0, of7 = o11 + ix1;

        // sample this thread's 8 channels
#pragma unroll
        for (int cc = 0; cc < 8; cc++) {
            const float* __restrict__ xb = x + (c0 + cc) * CSTRIDE;
            float s = cw0 * xb[of0] + cw1 * xb[of1] + cw2 * xb[of2] + cw3 * xb[of3]
                    + cw4 * xb[of4] + cw5 * xb[of5] + cw6 * xb[of6] + cw7 * xb[of7];
            sbuf[(c0 + cc) * 65 + lw] = m * s;
        }
        __syncthreads();

        // einsum partial: acc2[co] += sum_ci sbuf[ci][w] * w[co][ci][k]
        const float* __restrict__ wk = wt3 + k * 1024 + gu * 8;  // [ci][co32] slice
#pragma unroll 8
        for (int ci = 0; ci < 32; ci++) {
            float sv = sbuf[ci * 65 + lw];
#pragma unroll
            for (int j = 0; j < 8; j++)
                acc2[j] = fmaf(sv, wk[ci * 32 + j], acc2[j]);
        }
        __syncthreads();   // before next k overwrites sbuf
    }

    // ---------------- Epilogue ----------------
    int sp = (d * HH + h) * WW + lw;
#pragma unroll
    for (int j = 0; j < 8; j++)
        out[(c0 + j) * CSTRIDE + sp] = acc2[j] + bias[c0 + j];
}

// ---------------------------------------------------------------------------
extern "C" void kernel_launch(void* const* d_in, const int* in_sizes, int n_in,
                              void* d_out, int out_size, void* d_ws, size_t ws_size,
                              hipStream_t stream) {
    const float* x      = (const float*)d_in[0];
    const float* w_off  = (const float*)d_in[1];
    const float* b_off  = (const float*)d_in[2];
    const float* w_mask = (const float*)d_in[3];
    const float* b_mask = (const float*)d_in[4];
    const float* w      = (const float*)d_in[5];
    const float* b      = (const float*)d_in[6];
    float* out = (float*)d_out;

    float* wt2 = (float*)d_ws;          // 93312 floats
    float* wt3 = wt2 + 93312;           // 27648 floats  (total ~484 KB of ws)

    hipLaunchKernelGGL(transpose_w_kernel, dim3((120960 + 255) / 256), dim3(256), 0, stream,
                       w_off, w_mask, w, wt2, wt3);
    hipLaunchKernelGGL(deform_fused_kernel, dim3(DD * HH), dim3(256), 0, stream,
                       x, b_off, b_mask, b, wt2, wt3, out);
}

// Round 2
// 277.619 us; speedup vs baseline: 4.2042x; 4.2042x over previous
//
#include <hip/hip_runtime.h>
#include <math.h>

// Problem constants: B=1, CIN=COUT=32, KS=3 (K=27), D=32, H=W=64, stride=1, pad=1, dil=1
#define DD 32
#define HH 64
#define WW 64
#define CSTRIDE (DD * HH * WW)   // 131072
#define NPOS (DD * HH * WW)

typedef __attribute__((ext_vector_type(8))) short  short8;   // 8 bf16 (4 VGPRs) MFMA A/B frag
typedef __attribute__((ext_vector_type(4))) float  float4v;  // MFMA C/D frag

__device__ __forceinline__ float bf2f(unsigned short u) {
    unsigned v = ((unsigned)u) << 16;
    return __builtin_bit_cast(float, v);
}
__device__ __forceinline__ unsigned short f2bf(float f) {
    unsigned u = __builtin_bit_cast(unsigned, f);
    u = u + 0x7FFFu + ((u >> 16) & 1u);        // round-to-nearest-even
    return (unsigned short)(u >> 16);
}

// ---------------------------------------------------------------------------
// prep_x: x[ci][pos] fp32  ->  xT[pos][ci] bf16  (8.4 MB, channel-contiguous)
// One thread per pos: 32 coalesced loads, one 64B store.
// ---------------------------------------------------------------------------
__global__ __launch_bounds__(256) void prep_x(const float* __restrict__ x,
                                              unsigned short* __restrict__ xT)
{
    int pos = blockIdx.x * 256 + threadIdx.x;      // grid = 512 blocks
    unsigned short tmp[32] __attribute__((aligned(16)));
#pragma unroll
    for (int ci = 0; ci < 32; ci++)
        tmp[ci] = f2bf(x[ci * CSTRIDE + pos]);
    short8* dst = (short8*)(xT + pos * 32);
    const short8* src = (const short8*)tmp;
#pragma unroll
    for (int o = 0; o < 4; o++) dst[o] = src[o];
}

// ---------------------------------------------------------------------------
// prep_w: swizzle weights into exact per-lane MFMA A-fragment order (bf16).
//   A-frag (16x16x32): lane l holds A[m = l&15][k = (l>>4)*8 + j], j=0..7.
//   wAc[tap][mt(7)][lane][8]: conv weights, m=conv-ch (0..80 w_off, 81..107
//                             w_mask, >=108 zero), k=ci.
//   wAe[tap][mt(2)][lane][8]: einsum weights, m=co, k=ci.
// ---------------------------------------------------------------------------
__global__ __launch_bounds__(256) void prep_w(const float* __restrict__ w_off,
                                              const float* __restrict__ w_mask,
                                              const float* __restrict__ w,
                                              unsigned short* __restrict__ wAc,
                                              unsigned short* __restrict__ wAe)
{
    int i = blockIdx.x * 256 + threadIdx.x;
    if (i < 27 * 7 * 64 * 8) {                       // 96768
        int j    = i & 7;
        int lane = (i >> 3) & 63;
        int fm   = i >> 9;
        int mt   = fm % 7;
        int tap  = fm / 7;
        int ch   = mt * 16 + (lane & 15);
        int ci   = (lane >> 4) * 8 + j;
        float v = 0.f;
        if (ch < 81)       v = w_off[(ch * 32 + ci) * 27 + tap];
        else if (ch < 108) v = w_mask[((ch - 81) * 32 + ci) * 27 + tap];
        wAc[i] = f2bf(v);
    } else if (i < 96768 + 27 * 2 * 64 * 8) {        // + 27648
        int i2   = i - 96768;
        int j    = i2 & 7;
        int lane = (i2 >> 3) & 63;
        int fm   = i2 >> 9;
        int mt   = fm % 2;
        int tap  = fm / 2;
        int co   = mt * 16 + (lane & 15);
        int ci   = (lane >> 4) * 8 + j;
        wAe[i2] = f2bf(w[(co * 32 + ci) * 27 + tap]);
    }
}

// ---------------------------------------------------------------------------
// Main fused kernel. Block = 256 thr = 4 waves, one block per (d,h) row.
// Wave wv owns w-tile [wv*16, wv*16+16); lane l = (q<<4)|wl, q=ci-octet, wl=w.
// NO barriers: each wave's LDS columns are private.
//
// Phase 1 (conv -> offsets+mask): D[ch 112][w 16] via 16x16x32 bf16 MFMA.
//   B-frag = xT patch: lane reads 16B at xT[pos(w+kx-1)][q*8]  (B[k][n] layout).
//   A-frag = wAc (pre-swizzled), 7 m-tiles.
// Phase 2 (sample + einsum): lane samples its 8 ci at its w per tap (8 corner
//   loads of 16B each = 8 channels/load), packs bf16 -> that IS the B-frag of
//   the einsum MFMA. 2 MFMAs/tap accumulate D[co 32][w 16].
// ---------------------------------------------------------------------------
__global__ __launch_bounds__(256) void deform_mfma_kernel(
    const unsigned short* __restrict__ xT,
    const unsigned short* __restrict__ wAc,
    const unsigned short* __restrict__ wAe,
    const float* __restrict__ b_off, const float* __restrict__ b_mask,
    const float* __restrict__ bias, float* __restrict__ out)
{
    __shared__ float offm[108 * 65];   // [ch][wcol], pitch 65 (conflict-free)

    const int t    = threadIdx.x;
    const int lane = t & 63;
    const int wv   = t >> 6;
    const int wl   = lane & 15;
    const int q    = lane >> 4;
    const int d    = blockIdx.x >> 6;
    const int h    = blockIdx.x & 63;
    const int wcol = wv * 16 + wl;               // this lane's w position

    // ---------------- Phase 1: offset/mask conv via MFMA ----------------
    float4v acc[7];
#pragma unroll
    for (int mt = 0; mt < 7; mt++) acc[mt] = (float4v){0.f, 0.f, 0.f, 0.f};

    for (int tap = 0; tap < 27; tap++) {
        int kz = tap / 9, ky = (tap / 3) % 3, kx = tap % 3;
        int z = d + kz - 1, y = h + ky - 1;
        if ((unsigned)z >= (unsigned)DD || (unsigned)y >= (unsigned)HH)
            continue;                             // uniform: padded plane = 0
        int wx  = wcol + kx - 1;
        bool ok = (unsigned)wx < (unsigned)WW;    // per-lane only at w edges
        int pos = (z * HH + y) * WW + (ok ? wx : 0);

        short8 b = *(const short8*)(xT + pos * 32 + q * 8);
        if (!ok) b = (short8)0;                   // zero-pad columns

        const unsigned short* ap = wAc + (size_t)(tap * 7 * 64 + lane) * 8;
#pragma unroll
        for (int mt = 0; mt < 7; mt++) {
            short8 a = *(const short8*)(ap + mt * 64 * 8);
            acc[mt] = __builtin_amdgcn_mfma_f32_16x16x32_bf16(a, b, acc[mt], 0, 0, 0);
        }
    }

    // epilogue: bias + sigmoid(mask), store to this wave's LDS columns.
    // C/D layout: col = lane&15 (n=w), row = (lane>>4)*4 + r (m=ch).
#pragma unroll
    for (int mt = 0; mt < 7; mt++) {
#pragma unroll
        for (int r = 0; r < 4; r++) {
            int ch = mt * 16 + q * 4 + r;
            if (ch < 108) {
                float v = acc[mt][r] + (ch < 81 ? b_off[ch] : b_mask[ch - 81]);
                if (ch >= 81) v = 1.f / (1.f + __expf(-v));
                offm[ch * 65 + wcol] = v;
            }
        }
    }
    // no __syncthreads(): each wave reads back only columns it wrote;
    // compiler orders same-wave LDS via lgkmcnt.

    // ---------------- Phase 2: deformable sampling + einsum MFMA ----------------
    float4v acc2[2];
    acc2[0] = (float4v){0.f, 0.f, 0.f, 0.f};
    acc2[1] = (float4v){0.f, 0.f, 0.f, 0.f};

    for (int tap = 0; tap < 27; tap++) {
        int kz = tap / 9, ky = (tap / 3) % 3, kx = tap % 3;
        float oz = offm[(tap)      * 65 + wcol];
        float oy = offm[(27 + tap) * 65 + wcol];
        float ox = offm[(54 + tap) * 65 + wcol];
        float m  = offm[(81 + tap) * 65 + wcol];

        float zc = (float)(d + kz - 1) + oz;
        float yc = (float)(h + ky - 1) + oy;
        float xc = (float)(wcol + kx - 1) + ox;
        float zf = floorf(zc), yf = floorf(yc), xf = floorf(xc);
        int z0 = (int)zf, y0 = (int)yf, x0 = (int)xf;
        float fz = zc - zf, fy = yc - yf, fx = xc - xf;

        // per-axis validity folded into lerp weights (zero padding)
        float wz0 = (z0 >= 0 && z0 < DD)         ? (1.f - fz) : 0.f;
        float wz1 = (z0 + 1 >= 0 && z0 + 1 < DD) ? fz         : 0.f;
        float wy0 = (y0 >= 0 && y0 < HH)         ? (1.f - fy) : 0.f;
        float wy1 = (y0 + 1 >= 0 && y0 + 1 < HH) ? fy         : 0.f;
        float wx0 = (x0 >= 0 && x0 < WW)         ? (1.f - fx) : 0.f;
        float wx1 = (x0 + 1 >= 0 && x0 + 1 < WW) ? fx         : 0.f;

        int iz0 = min(max(z0, 0), DD - 1), iz1 = min(max(z0 + 1, 0), DD - 1);
        int iy0 = min(max(y0, 0), HH - 1), iy1 = min(max(y0 + 1, 0), HH - 1);
        int ix0 = min(max(x0, 0), WW - 1), ix1 = min(max(x0 + 1, 0), WW - 1);

        int o00 = (iz0 * HH + iy0) * WW, o01 = (iz0 * HH + iy1) * WW;
        int o10 = (iz1 * HH + iy0) * WW, o11 = (iz1 * HH + iy1) * WW;

        // corner weights, mask folded in (val = m * trilerp)
        float cw[8];
        cw[0] = m * wz0 * wy0 * wx0; cw[1] = m * wz0 * wy0 * wx1;
        cw[2] = m * wz0 * wy1 * wx0; cw[3] = m * wz0 * wy1 * wx1;
        cw[4] = m * wz1 * wy0 * wx0; cw[5] = m * wz1 * wy0 * wx1;
        cw[6] = m * wz1 * wy1 * wx0; cw[7] = m * wz1 * wy1 * wx1;
        int ofs[8];
        ofs[0] = o00 + ix0; ofs[1] = o00 + ix1; ofs[2] = o01 + ix0; ofs[3] = o01 + ix1;
        ofs[4] = o10 + ix0; ofs[5] = o10 + ix1; ofs[6] = o11 + ix0; ofs[7] = o11 + ix1;

        // 8 corner loads, each 16B = this lane's 8 channels (octet q)
        short8 cnr[8];
#pragma unroll
        for (int c = 0; c < 8; c++)
            cnr[c] = *(const short8*)(xT + ofs[c] * 32 + q * 8);

        float v[8];
#pragma unroll
        for (int j = 0; j < 8; j++) v[j] = 0.f;
#pragma unroll
        for (int c = 0; c < 8; c++) {
            float cwc = cw[c];
#pragma unroll
            for (int j = 0; j < 8; j++)
                v[j] = fmaf(cwc, bf2f((unsigned short)cnr[c][j]), v[j]);
        }

        // pack sampled octet -> einsum B-frag (B[k=q*8+j][n=wl]); MFMA x2
        short8 bfr;
#pragma unroll
        for (int j = 0; j < 8; j++) bfr[j] = (short)f2bf(v[j]);

        const unsigned short* aep = wAe + (size_t)(tap * 2 * 64 + lane) * 8;
        short8 a0 = *(const short8*)(aep);
        short8 a1 = *(const short8*)(aep + 64 * 8);
        acc2[0] = __builtin_amdgcn_mfma_f32_16x16x32_bf16(a0, bfr, acc2[0], 0, 0, 0);
        acc2[1] = __builtin_amdgcn_mfma_f32_16x16x32_bf16(a1, bfr, acc2[1], 0, 0, 0);
    }

    // ---------------- Epilogue: C/D layout -> global ----------------
    int sp = (d * HH + h) * WW + wcol;
#pragma unroll
    for (int mt = 0; mt < 2; mt++) {
#pragma unroll
        for (int r = 0; r < 4; r++) {
            int co = mt * 16 + q * 4 + r;
            out[co * CSTRIDE + sp] = acc2[mt][r] + bias[co];
        }
    }
}

// ---------------------------------------------------------------------------
extern "C" void kernel_launch(void* const* d_in, const int* in_sizes, int n_in,
                              void* d_out, int out_size, void* d_ws, size_t ws_size,
                              hipStream_t stream) {
    const float* x      = (const float*)d_in[0];
    const float* w_off  = (const float*)d_in[1];
    const float* b_off  = (const float*)d_in[2];
    const float* w_mask = (const float*)d_in[3];
    const float* b_mask = (const float*)d_in[4];
    const float* w      = (const float*)d_in[5];
    const float* b      = (const float*)d_in[6];
    float* out = (float*)d_out;

    // workspace layout (all 16B aligned): xT 8,388,608 B | wAc 193,536 B | wAe 55,296 B
    unsigned short* xT  = (unsigned short*)d_ws;
    unsigned short* wAc = xT + (size_t)NPOS * 32;
    unsigned short* wAe = wAc + 27 * 7 * 64 * 8;

    hipLaunchKernelGGL(prep_x, dim3(NPOS / 256), dim3(256), 0, stream, x, xT);
    hipLaunchKernelGGL(prep_w, dim3((96768 + 27648 + 255) / 256), dim3(256), 0, stream,
                       w_off, w_mask, w, wAc, wAe);
    hipLaunchKernelGGL(deform_mfma_kernel, dim3(DD * HH), dim3(256), 0, stream,
                       xT, wAc, wAe, b_off, b_mask, b, out);
}